// Round 1
// baseline (575.334 us; speedup 1.0000x reference)
//
#include <hip/hip_runtime.h>
#include <hip/hip_bf16.h>
#include <stdint.h>

// Problem constants
#define DM   1024
#define NH   16
#define DH   64
#define BATCH 4
#define SEQ  2048
#define MROWS (BATCH*SEQ)   // 8192

typedef float f32x4 __attribute__((ext_vector_type(4)));
typedef __bf16 bf16x8 __attribute__((ext_vector_type(8)));

__device__ __forceinline__ short f2bs(float f) {
    __bf16 h = (__bf16)f;
    return __builtin_bit_cast(short, h);
}

__device__ __forceinline__ void gload_lds16(const void* g, void* l) {
    __builtin_amdgcn_global_load_lds(
        (__attribute__((address_space(1))) void*)(g),
        (__attribute__((address_space(3))) void*)(l), 16, 0, 0);
}

// ---------------------------------------------------------------------------
// Transpose + fp32->bf16 convert: wt[n][k] = bf16(w[k][n]).  64x64 tiles.
// ---------------------------------------------------------------------------
__global__ __launch_bounds__(256) void transpose_cvt_kernel(
    const float* __restrict__ w, short* __restrict__ wt, int K, int N)
{
    __shared__ short tile[64 * 65];
    const int k0 = blockIdx.x * 64, n0 = blockIdx.y * 64;
    const int t = threadIdx.x;
#pragma unroll
    for (int i = 0; i < 16; ++i) {
        int idx = i * 256 + t;
        int r = idx >> 6, c = idx & 63;
        tile[r * 65 + c] = f2bs(w[(size_t)(k0 + r) * N + n0 + c]);
    }
    __syncthreads();
#pragma unroll
    for (int i = 0; i < 16; ++i) {
        int idx = i * 256 + t;
        int r = idx >> 6, c = idx & 63;      // r: n-local, c: k-local
        wt[(size_t)(n0 + r) * K + k0 + c] = tile[c * 65 + r];
    }
}

// ---------------------------------------------------------------------------
// LayerNorm (rows of 1024 fp32) -> bf16
// ---------------------------------------------------------------------------
__global__ __launch_bounds__(256) void ln_kernel(
    const float* __restrict__ x, const float* __restrict__ g,
    const float* __restrict__ be, short* __restrict__ out)
{
    const int row = blockIdx.x, t = threadIdx.x;
    const float4 v = ((const float4*)(x + (size_t)row * DM))[t];
    float s  = v.x + v.y + v.z + v.w;
    float ss = v.x * v.x + v.y * v.y + v.z * v.z + v.w * v.w;
#pragma unroll
    for (int d = 1; d < 64; d <<= 1) {
        s  += __shfl_xor(s, d, 64);
        ss += __shfl_xor(ss, d, 64);
    }
    __shared__ float red[8];
    const int wid = t >> 6;
    if ((t & 63) == 0) { red[wid] = s; red[wid + 4] = ss; }
    __syncthreads();
    s  = red[0] + red[1] + red[2] + red[3];
    ss = red[4] + red[5] + red[6] + red[7];
    const float mu = s * (1.0f / DM);
    const float rs = rsqrtf(ss * (1.0f / DM) - mu * mu + 1e-5f);
    const float4 gg = ((const float4*)g)[t];
    const float4 bb = ((const float4*)be)[t];
    short4 o;
    o.x = f2bs((v.x - mu) * rs * gg.x + bb.x);
    o.y = f2bs((v.y - mu) * rs * gg.y + bb.y);
    o.z = f2bs((v.z - mu) * rs * gg.z + bb.z);
    o.w = f2bs((v.w - mu) * rs * gg.w + bb.w);
    ((short4*)(out + (size_t)row * DM))[t] = o;
}

// ---------------------------------------------------------------------------
// GEMM: C[M,N] = A[M,K] @ B[K,N], A bf16 row-major, Bt bf16 [N][K].
// 128x128 tile, BK=32, 4 waves (2x2), each wave 64x64 via 4x4 mfma 16x16x32.
// EPI 0: QKV scatter (Q,K -> [BH,T,64]; V -> [BH,64,T])
// EPI 1: out fp32 = acc + bias[n] + res[m,n]
// EPI 2: out bf16 = relu(acc + bias[n])
// ---------------------------------------------------------------------------
template<int EPI>
__global__ __launch_bounds__(256) void gemm_bt(
    const short* __restrict__ A, const short* __restrict__ Bt,
    int N, int K,
    const float* __restrict__ bias, const float* __restrict__ res,
    float* __restrict__ outf, short* __restrict__ outb,
    short* __restrict__ qo, short* __restrict__ ko, short* __restrict__ vo)
{
    __shared__ short As[128 * 32];
    __shared__ short Bs[128 * 32];
    const int t = threadIdx.x;
    const int lane = t & 63;
    const int l15 = lane & 15, hi = lane >> 4;
    const int wid = t >> 6;
    const int wm = (wid & 1) * 64, wn = (wid >> 1) * 64;
    const int m0 = blockIdx.x * 128, n0 = blockIdx.y * 128;

    f32x4 acc[4][4] = {};

    const int ra = t >> 2;            // row for staging chunk (0..63)
    const int ca = (t & 3) * 8;       // k-offset in shorts

    for (int k0 = 0; k0 < K; k0 += 32) {
        gload_lds16(A  + (size_t)(m0 + ra)      * K + k0 + ca, &As[t * 8]);
        gload_lds16(A  + (size_t)(m0 + ra + 64) * K + k0 + ca, &As[(t + 256) * 8]);
        gload_lds16(Bt + (size_t)(n0 + ra)      * K + k0 + ca, &Bs[t * 8]);
        gload_lds16(Bt + (size_t)(n0 + ra + 64) * K + k0 + ca, &Bs[(t + 256) * 8]);
        __syncthreads();
        bf16x8 af[4], bfr[4];
#pragma unroll
        for (int i = 0; i < 4; ++i)
            af[i] = *(const bf16x8*)&As[(wm + i * 16 + l15) * 32 + hi * 8];
#pragma unroll
        for (int j = 0; j < 4; ++j)
            bfr[j] = *(const bf16x8*)&Bs[(wn + j * 16 + l15) * 32 + hi * 8];
#pragma unroll
        for (int i = 0; i < 4; ++i)
#pragma unroll
            for (int j = 0; j < 4; ++j)
                acc[i][j] = __builtin_amdgcn_mfma_f32_16x16x32_bf16(
                    af[i], bfr[j], acc[i][j], 0, 0, 0);
        __syncthreads();
    }

    const int rbase = m0 + wm + hi * 4;
    const int cb = n0 + wn + l15;
#pragma unroll
    for (int i = 0; i < 4; ++i) {
#pragma unroll
        for (int j = 0; j < 4; ++j) {
            const int nn = cb + j * 16;
            if constexpr (EPI == 0) {
                const int mat = nn >> 10, n1 = nn & 1023;
                const int head = n1 >> 6, dh = n1 & 63;
#pragma unroll
                for (int r = 0; r < 4; ++r) {
                    const int m = rbase + i * 16 + r;
                    const int b = m >> 11, tok = m & 2047;
                    const size_t bh = (size_t)(b * NH + head);
                    const short v = f2bs(acc[i][j][r]);
                    if (mat == 0)      qo[(bh * SEQ + tok) * DH + dh] = v;
                    else if (mat == 1) ko[(bh * SEQ + tok) * DH + dh] = v;
                    else               vo[(bh * DH + dh) * SEQ + tok] = v;
                }
            } else if constexpr (EPI == 1) {
#pragma unroll
                for (int r = 0; r < 4; ++r) {
                    const int m = rbase + i * 16 + r;
                    outf[(size_t)m * N + nn] =
                        acc[i][j][r] + bias[nn] + res[(size_t)m * N + nn];
                }
            } else {
#pragma unroll
                for (int r = 0; r < 4; ++r) {
                    const int m = rbase + i * 16 + r;
                    float z = acc[i][j][r] + bias[nn];
                    outb[(size_t)m * N + nn] = f2bs(z > 0.f ? z : 0.f);
                }
            }
        }
    }
}

// ---------------------------------------------------------------------------
// Causal flash attention. grid = (T/128, B*H). 4 waves x 32 q-rows.
// Q,K: [BH, T, 64] bf16.  Vt: [BH, 64, T] bf16.  out att: [B*T, 1024] bf16.
// ---------------------------------------------------------------------------
__global__ __launch_bounds__(256) void attn_kernel(
    const short* __restrict__ Q, const short* __restrict__ Kx,
    const short* __restrict__ Vt, short* __restrict__ att)
{
    __shared__ short Ks[64 * 72];
    __shared__ short Vs[64 * 72];
    __shared__ short Ps[4][32 * 72];

    const int qi = blockIdx.x, bh = blockIdx.y;
    const int t = threadIdx.x, lane = t & 63, wid = t >> 6;
    const int l15 = lane & 15, hi = lane >> 4;
    const int qb0 = qi * 128;
    const int qw0 = qb0 + wid * 32;
    const size_t base = (size_t)bh * (SEQ * DH);

    bf16x8 qf[2][2];
#pragma unroll
    for (int mf = 0; mf < 2; ++mf)
#pragma unroll
        for (int kf = 0; kf < 2; ++kf)
            qf[mf][kf] = *(const bf16x8*)
                &Q[base + (size_t)(qw0 + mf * 16 + l15) * DH + kf * 32 + hi * 8];

    f32x4 O[2][4] = {};
    float Mx[2][4], L[2][4];
#pragma unroll
    for (int mf = 0; mf < 2; ++mf)
#pragma unroll
        for (int r = 0; r < 4; ++r) { Mx[mf][r] = -3.0e38f; L[mf][r] = 0.f; }

    const int nkv = qb0 / 64 + 2;
    for (int it = 0; it < nkv; ++it) {
        const int kv0 = it * 64;
#pragma unroll
        for (int i = 0; i < 2; ++i) {
            int c = i * 256 + t;
            int row = c >> 3, cc = (c & 7) * 8;
            *(int4*)&Ks[row * 72 + cc] =
                *(const int4*)&Kx[base + (size_t)(kv0 + row) * DH + cc];
            *(int4*)&Vs[row * 72 + cc] =
                *(const int4*)&Vt[base + (size_t)row * SEQ + kv0 + cc];
        }
        __syncthreads();

        f32x4 S[2][4] = {};
        bf16x8 kfr[4][2];
#pragma unroll
        for (int nf = 0; nf < 4; ++nf)
#pragma unroll
            for (int kf = 0; kf < 2; ++kf)
                kfr[nf][kf] = *(const bf16x8*)&Ks[(nf * 16 + l15) * 72 + kf * 32 + hi * 8];
#pragma unroll
        for (int kf = 0; kf < 2; ++kf)
#pragma unroll
            for (int mf = 0; mf < 2; ++mf)
#pragma unroll
                for (int nf = 0; nf < 4; ++nf)
                    S[mf][nf] = __builtin_amdgcn_mfma_f32_16x16x32_bf16(
                        qf[mf][kf], kfr[nf][kf], S[mf][nf], 0, 0, 0);

        const bool tail = (kv0 + 63) > qw0;
#pragma unroll
        for (int mf = 0; mf < 2; ++mf)
#pragma unroll
            for (int nf = 0; nf < 4; ++nf)
#pragma unroll
                for (int r = 0; r < 4; ++r) {
                    float v = S[mf][nf][r] * 0.03125f;   // 1/sqrt(1024)
                    if (tail) {
                        int q  = qw0 + mf * 16 + hi * 4 + r;
                        int kv = kv0 + nf * 16 + l15;
                        if (kv > q) v = -3.0e38f;
                    }
                    S[mf][nf][r] = v;
                }

#pragma unroll
        for (int mf = 0; mf < 2; ++mf) {
            float mx[4], f[4], ps[4];
#pragma unroll
            for (int r = 0; r < 4; ++r) {
                float m_ = fmaxf(fmaxf(S[mf][0][r], S[mf][1][r]),
                                 fmaxf(S[mf][2][r], S[mf][3][r]));
                mx[r] = m_;
            }
#pragma unroll
            for (int d = 1; d < 16; d <<= 1)
#pragma unroll
                for (int r = 0; r < 4; ++r)
                    mx[r] = fmaxf(mx[r], __shfl_xor(mx[r], d, 64));
#pragma unroll
            for (int r = 0; r < 4; ++r) {
                float Mn = fmaxf(Mx[mf][r], mx[r]);
                f[r] = __expf(Mx[mf][r] - Mn);
                Mx[mf][r] = Mn;
                ps[r] = 0.f;
            }
#pragma unroll
            for (int nf = 0; nf < 4; ++nf)
#pragma unroll
                for (int r = 0; r < 4; ++r) {
                    float p = __expf(S[mf][nf][r] - Mx[mf][r]);
                    S[mf][nf][r] = p;
                    ps[r] += p;
                }
#pragma unroll
            for (int d = 1; d < 16; d <<= 1)
#pragma unroll
                for (int r = 0; r < 4; ++r)
                    ps[r] += __shfl_xor(ps[r], d, 64);
#pragma unroll
            for (int r = 0; r < 4; ++r)
                L[mf][r] = L[mf][r] * f[r] + ps[r];
#pragma unroll
            for (int nf = 0; nf < 4; ++nf)
#pragma unroll
                for (int r = 0; r < 4; ++r)
                    O[mf][nf][r] *= f[r];
#pragma unroll
            for (int nf = 0; nf < 4; ++nf)
#pragma unroll
                for (int r = 0; r < 4; ++r)
                    Ps[wid][(mf * 16 + hi * 4 + r) * 72 + nf * 16 + l15] =
                        f2bs(S[mf][nf][r]);
        }

        bf16x8 pf[2][2], vf[4][2];
#pragma unroll
        for (int mf = 0; mf < 2; ++mf)
#pragma unroll
            for (int kf = 0; kf < 2; ++kf)
                pf[mf][kf] = *(const bf16x8*)&Ps[wid][(mf * 16 + l15) * 72 + kf * 32 + hi * 8];
#pragma unroll
        for (int nf = 0; nf < 4; ++nf)
#pragma unroll
            for (int kf = 0; kf < 2; ++kf)
                vf[nf][kf] = *(const bf16x8*)&Vs[(nf * 16 + l15) * 72 + kf * 32 + hi * 8];
#pragma unroll
        for (int kf = 0; kf < 2; ++kf)
#pragma unroll
            for (int mf = 0; mf < 2; ++mf)
#pragma unroll
                for (int nf = 0; nf < 4; ++nf)
                    O[mf][nf] = __builtin_amdgcn_mfma_f32_16x16x32_bf16(
                        pf[mf][kf], vf[nf][kf], O[mf][nf], 0, 0, 0);

        __syncthreads();
    }

    const int b = bh >> 4, head = bh & 15;
#pragma unroll
    for (int mf = 0; mf < 2; ++mf)
#pragma unroll
        for (int nf = 0; nf < 4; ++nf)
#pragma unroll
            for (int r = 0; r < 4; ++r) {
                const int q = qw0 + mf * 16 + hi * 4 + r;
                const float val = O[mf][nf][r] / L[mf][r];
                att[(size_t)(b * SEQ + q) * DM + head * DH + nf * 16 + l15] = f2bs(val);
            }
}

// ---------------------------------------------------------------------------
extern "C" void kernel_launch(void* const* d_in, const int* in_sizes, int n_in,
                              void* d_out, int out_size, void* d_ws, size_t ws_size,
                              hipStream_t stream) {
    const float* x   = (const float*)d_in[0];
    const float* wq  = (const float*)d_in[1];
    const float* wk  = (const float*)d_in[2];
    const float* wv  = (const float*)d_in[3];
    const float* wp  = (const float*)d_in[4];
    const float* bp  = (const float*)d_in[5];
    const float* w1  = (const float*)d_in[6];
    const float* b1  = (const float*)d_in[7];
    const float* w2  = (const float*)d_in[8];
    const float* b2  = (const float*)d_in[9];
    const float* g1  = (const float*)d_in[10];
    const float* be1 = (const float*)d_in[11];
    const float* g2  = (const float*)d_in[12];
    const float* be2 = (const float*)d_in[13];
    float* out = (float*)d_out;

    char* ws = (char*)d_ws;
    short* wqkv_t = (short*)(ws + 0);          //  6.0 MB  [3072][1024]
    short* wp_t   = (short*)(ws + 6291456);    //  2.0 MB  [1024][1024]
    short* w1_t   = (short*)(ws + 8388608);    //  8.0 MB  [4096][1024]
    short* w2_t   = (short*)(ws + 16777216);   //  8.0 MB  [1024][4096]
    short* h      = (short*)(ws + 25165824);   // 16 MB
    short* qb     = (short*)(ws + 41943040);   // 16 MB
    short* kb     = (short*)(ws + 58720256);   // 16 MB
    short* vb     = (short*)(ws + 75497472);   // 16 MB
    short* att    = (short*)(ws + 92274688);   // 16 MB
    float* x1     = (float*)(ws + 109051904);  // 32 MB
    short* h2     = (short*)(ws + 142606336);  // 16 MB
    short* tbuf   = (short*)(ws + 25165824);   // 64 MB, aliases h/qb/kb/vb (dead)

    dim3 blk(256);

    transpose_cvt_kernel<<<dim3(16, 16), blk, 0, stream>>>(wq, wqkv_t,                1024, 1024);
    transpose_cvt_kernel<<<dim3(16, 16), blk, 0, stream>>>(wk, wqkv_t + 1024 * 1024,  1024, 1024);
    transpose_cvt_kernel<<<dim3(16, 16), blk, 0, stream>>>(wv, wqkv_t + 2048 * 1024,  1024, 1024);
    transpose_cvt_kernel<<<dim3(16, 16), blk, 0, stream>>>(wp, wp_t,                  1024, 1024);
    transpose_cvt_kernel<<<dim3(16, 64), blk, 0, stream>>>(w1, w1_t,                  1024, 4096);
    transpose_cvt_kernel<<<dim3(64, 16), blk, 0, stream>>>(w2, w2_t,                  4096, 1024);

    ln_kernel<<<MROWS, blk, 0, stream>>>(x, g1, be1, h);

    gemm_bt<0><<<dim3(64, 24), blk, 0, stream>>>(h, wqkv_t, 3072, 1024,
        nullptr, nullptr, nullptr, nullptr, qb, kb, vb);

    attn_kernel<<<dim3(16, 64), blk, 0, stream>>>(qb, kb, vb, att);

    gemm_bt<1><<<dim3(64, 8), blk, 0, stream>>>(att, wp_t, 1024, 1024,
        bp, x, x1, nullptr, nullptr, nullptr, nullptr);

    ln_kernel<<<MROWS, blk, 0, stream>>>(x1, g2, be2, h2);

    gemm_bt<2><<<dim3(64, 32), blk, 0, stream>>>(h2, w1_t, 4096, 1024,
        b1, nullptr, nullptr, tbuf, nullptr, nullptr, nullptr);

    gemm_bt<1><<<dim3(64, 8), blk, 0, stream>>>(tbuf, w2_t, 1024, 4096,
        b2, x1, out, nullptr, nullptr, nullptr, nullptr);
}

// Round 2
// 560.922 us; speedup vs baseline: 1.0257x; 1.0257x over previous
//
#include <hip/hip_runtime.h>
#include <hip/hip_bf16.h>
#include <stdint.h>

// Problem constants
#define DM   1024
#define NH   16
#define DH   64
#define BATCH 4
#define SEQ  2048
#define MROWS (BATCH*SEQ)   // 8192

typedef float f32x4 __attribute__((ext_vector_type(4)));
typedef __bf16 bf16x8 __attribute__((ext_vector_type(8)));

// Q is pre-scaled by (1/sqrt(D)) * log2(e) so softmax can use exp2 directly.
#define QSCALE 0.045084220f

__device__ __forceinline__ short f2bs(float f) {
    __bf16 h = (__bf16)f;
    return __builtin_bit_cast(short, h);
}

__device__ __forceinline__ void gload_lds16(const void* g, void* l) {
    __builtin_amdgcn_global_load_lds(
        (__attribute__((address_space(1))) void*)(g),
        (__attribute__((address_space(3))) void*)(l), 16, 0, 0);
}

// ---------------------------------------------------------------------------
// Transpose + fp32->bf16 convert: wt[n][k] = bf16(w[k][n]).  64x64 tiles.
// ---------------------------------------------------------------------------
__global__ __launch_bounds__(256) void transpose_cvt_kernel(
    const float* __restrict__ w, short* __restrict__ wt, int K, int N)
{
    __shared__ short tile[64 * 65];
    const int k0 = blockIdx.x * 64, n0 = blockIdx.y * 64;
    const int t = threadIdx.x;
#pragma unroll
    for (int i = 0; i < 16; ++i) {
        int idx = i * 256 + t;
        int r = idx >> 6, c = idx & 63;
        tile[r * 65 + c] = f2bs(w[(size_t)(k0 + r) * N + n0 + c]);
    }
    __syncthreads();
#pragma unroll
    for (int i = 0; i < 16; ++i) {
        int idx = i * 256 + t;
        int r = idx >> 6, c = idx & 63;      // r: n-local, c: k-local
        wt[(size_t)(n0 + r) * K + k0 + c] = tile[c * 65 + r];
    }
}

// ---------------------------------------------------------------------------
// LayerNorm (rows of 1024 fp32) -> bf16
// ---------------------------------------------------------------------------
__global__ __launch_bounds__(256) void ln_kernel(
    const float* __restrict__ x, const float* __restrict__ g,
    const float* __restrict__ be, short* __restrict__ out)
{
    const int row = blockIdx.x, t = threadIdx.x;
    const float4 v = ((const float4*)(x + (size_t)row * DM))[t];
    float s  = v.x + v.y + v.z + v.w;
    float ss = v.x * v.x + v.y * v.y + v.z * v.z + v.w * v.w;
#pragma unroll
    for (int d = 1; d < 64; d <<= 1) {
        s  += __shfl_xor(s, d, 64);
        ss += __shfl_xor(ss, d, 64);
    }
    __shared__ float red[8];
    const int wid = t >> 6;
    if ((t & 63) == 0) { red[wid] = s; red[wid + 4] = ss; }
    __syncthreads();
    s  = red[0] + red[1] + red[2] + red[3];
    ss = red[4] + red[5] + red[6] + red[7];
    const float mu = s * (1.0f / DM);
    const float rs = rsqrtf(ss * (1.0f / DM) - mu * mu + 1e-5f);
    const float4 gg = ((const float4*)g)[t];
    const float4 bb = ((const float4*)be)[t];
    short4 o;
    o.x = f2bs((v.x - mu) * rs * gg.x + bb.x);
    o.y = f2bs((v.y - mu) * rs * gg.y + bb.y);
    o.z = f2bs((v.z - mu) * rs * gg.z + bb.z);
    o.w = f2bs((v.w - mu) * rs * gg.w + bb.w);
    ((short4*)(out + (size_t)row * DM))[t] = o;
}

// ---------------------------------------------------------------------------
// GEMM: C[M,N] = A[M,K] @ B[K,N], A bf16 row-major, Bt bf16 [N][K].
// 128x128 tile, BK=32, 4 waves (2x2), each wave 64x64 via 4x4 mfma 16x16x32.
// EPI 0: QKV scatter (Q scaled by QSCALE, Q,K -> [BH,T,64]; V -> [BH,64,T])
// EPI 1: out fp32 = acc + bias[n] + res[m,n]
// EPI 2: out bf16 = relu(acc + bias[n])
// ---------------------------------------------------------------------------
template<int EPI>
__global__ __launch_bounds__(256) void gemm_bt(
    const short* __restrict__ A, const short* __restrict__ Bt,
    int N, int K,
    const float* __restrict__ bias, const float* __restrict__ res,
    float* __restrict__ outf, short* __restrict__ outb,
    short* __restrict__ qo, short* __restrict__ ko, short* __restrict__ vo)
{
    __shared__ short As[128 * 32];
    __shared__ short Bs[128 * 32];
    const int t = threadIdx.x;
    const int lane = t & 63;
    const int l15 = lane & 15, hi = lane >> 4;
    const int wid = t >> 6;
    const int wm = (wid & 1) * 64, wn = (wid >> 1) * 64;
    const int m0 = blockIdx.x * 128, n0 = blockIdx.y * 128;

    f32x4 acc[4][4] = {};

    const int ra = t >> 2;            // row for staging chunk (0..63)
    const int ca = (t & 3) * 8;       // k-offset in shorts

    for (int k0 = 0; k0 < K; k0 += 32) {
        gload_lds16(A  + (size_t)(m0 + ra)      * K + k0 + ca, &As[t * 8]);
        gload_lds16(A  + (size_t)(m0 + ra + 64) * K + k0 + ca, &As[(t + 256) * 8]);
        gload_lds16(Bt + (size_t)(n0 + ra)      * K + k0 + ca, &Bs[t * 8]);
        gload_lds16(Bt + (size_t)(n0 + ra + 64) * K + k0 + ca, &Bs[(t + 256) * 8]);
        __syncthreads();
        bf16x8 af[4], bfr[4];
#pragma unroll
        for (int i = 0; i < 4; ++i)
            af[i] = *(const bf16x8*)&As[(wm + i * 16 + l15) * 32 + hi * 8];
#pragma unroll
        for (int j = 0; j < 4; ++j)
            bfr[j] = *(const bf16x8*)&Bs[(wn + j * 16 + l15) * 32 + hi * 8];
#pragma unroll
        for (int i = 0; i < 4; ++i)
#pragma unroll
            for (int j = 0; j < 4; ++j)
                acc[i][j] = __builtin_amdgcn_mfma_f32_16x16x32_bf16(
                    af[i], bfr[j], acc[i][j], 0, 0, 0);
        __syncthreads();
    }

    const int rbase = m0 + wm + hi * 4;
    const int cb = n0 + wn + l15;
#pragma unroll
    for (int i = 0; i < 4; ++i) {
#pragma unroll
        for (int j = 0; j < 4; ++j) {
            const int nn = cb + j * 16;
            if constexpr (EPI == 0) {
                const int mat = nn >> 10, n1 = nn & 1023;
                const int head = n1 >> 6, dh = n1 & 63;
                if (mat == 2) {
                    // V: 4 consecutive tokens -> one short4 store
                    const int m = rbase + i * 16;
                    const int b = m >> 11, tok = m & 2047;
                    short4 pk;
                    pk.x = f2bs(acc[i][j][0]);
                    pk.y = f2bs(acc[i][j][1]);
                    pk.z = f2bs(acc[i][j][2]);
                    pk.w = f2bs(acc[i][j][3]);
                    *(short4*)&vo[((size_t)(b * NH + head) * DH + dh) * SEQ + tok] = pk;
                } else {
                    const float sc = (mat == 0) ? QSCALE : 1.0f;
#pragma unroll
                    for (int r = 0; r < 4; ++r) {
                        const int m = rbase + i * 16 + r;
                        const int b = m >> 11, tok = m & 2047;
                        const size_t bh = (size_t)(b * NH + head);
                        const short v = f2bs(acc[i][j][r] * sc);
                        if (mat == 0) qo[(bh * SEQ + tok) * DH + dh] = v;
                        else          ko[(bh * SEQ + tok) * DH + dh] = v;
                    }
                }
            } else if constexpr (EPI == 1) {
#pragma unroll
                for (int r = 0; r < 4; ++r) {
                    const int m = rbase + i * 16 + r;
                    outf[(size_t)m * N + nn] =
                        acc[i][j][r] + bias[nn] + res[(size_t)m * N + nn];
                }
            } else {
#pragma unroll
                for (int r = 0; r < 4; ++r) {
                    const int m = rbase + i * 16 + r;
                    float z = acc[i][j][r] + bias[nn];
                    outb[(size_t)m * N + nn] = f2bs(z > 0.f ? z : 0.f);
                }
            }
        }
    }
}

// ---------------------------------------------------------------------------
// Causal flash attention, ONE independent wave per (bh, 32 q-rows).
// No __syncthreads. K/V fragments loaded directly from global (L2-resident).
// Q: [BH,T,64] bf16 (pre-scaled by QSCALE). K: [BH,T,64]. Vt: [BH,64,T].
// out att: [B*T, 1024] bf16.  grid = (64, BH), block = 64.
// ---------------------------------------------------------------------------
__global__ __launch_bounds__(64) void attn_kernel(
    const short* __restrict__ Q, const short* __restrict__ Kx,
    const short* __restrict__ Vt, short* __restrict__ att)
{
    __shared__ short Ps[32 * 72];

    const int qi = 63 - blockIdx.x;          // long blocks dispatch first
    const int bh = blockIdx.y;
    const int lane = threadIdx.x;
    const int l15 = lane & 15, hi = lane >> 4;
    const int q0 = qi * 32;
    const size_t base = (size_t)bh * (SEQ * DH);

    bf16x8 qf[2][2];
#pragma unroll
    for (int mf = 0; mf < 2; ++mf)
#pragma unroll
        for (int kf = 0; kf < 2; ++kf)
            qf[mf][kf] = *(const bf16x8*)
                &Q[base + (size_t)(q0 + mf * 16 + l15) * DH + kf * 32 + hi * 8];

    f32x4 O[2][4] = {};
    float Mx[2][4], L[2][4];
#pragma unroll
    for (int mf = 0; mf < 2; ++mf)
#pragma unroll
        for (int r = 0; r < 4; ++r) { Mx[mf][r] = -3.0e38f; L[mf][r] = 0.f; }

    const int nkv = (q0 + 95) >> 6;
    for (int it = 0; it < nkv; ++it) {
        const int kv0 = it * 64;

        bf16x8 kfr[4][2];
#pragma unroll
        for (int nf = 0; nf < 4; ++nf)
#pragma unroll
            for (int kf = 0; kf < 2; ++kf)
                kfr[nf][kf] = *(const bf16x8*)
                    &Kx[base + (size_t)(kv0 + nf * 16 + l15) * DH + kf * 32 + hi * 8];

        f32x4 S[2][4] = {};
#pragma unroll
        for (int kf = 0; kf < 2; ++kf)
#pragma unroll
            for (int mf = 0; mf < 2; ++mf)
#pragma unroll
                for (int nf = 0; nf < 4; ++nf)
                    S[mf][nf] = __builtin_amdgcn_mfma_f32_16x16x32_bf16(
                        qf[mf][kf], kfr[nf][kf], S[mf][nf], 0, 0, 0);

        // prefetch V fragments (B-operand: rows = dh, k = kv)
        bf16x8 vf[4][2];
#pragma unroll
        for (int nf = 0; nf < 4; ++nf)
#pragma unroll
            for (int kf = 0; kf < 2; ++kf)
                vf[nf][kf] = *(const bf16x8*)
                    &Vt[base + (size_t)(nf * 16 + l15) * SEQ + kv0 + kf * 32 + hi * 8];

        if (kv0 + 63 > q0) {   // causal tail masking
#pragma unroll
            for (int mf = 0; mf < 2; ++mf)
#pragma unroll
                for (int nf = 0; nf < 4; ++nf)
#pragma unroll
                    for (int r = 0; r < 4; ++r) {
                        const int q  = q0 + mf * 16 + hi * 4 + r;
                        const int kv = kv0 + nf * 16 + l15;
                        if (kv > q) S[mf][nf][r] = -3.0e38f;
                    }
        }

#pragma unroll
        for (int mf = 0; mf < 2; ++mf) {
            float mx[4], f[4], ps[4];
#pragma unroll
            for (int r = 0; r < 4; ++r)
                mx[r] = fmaxf(fmaxf(S[mf][0][r], S[mf][1][r]),
                              fmaxf(S[mf][2][r], S[mf][3][r]));
#pragma unroll
            for (int d = 1; d < 16; d <<= 1)
#pragma unroll
                for (int r = 0; r < 4; ++r)
                    mx[r] = fmaxf(mx[r], __shfl_xor(mx[r], d, 64));
#pragma unroll
            for (int r = 0; r < 4; ++r) {
                const float Mn = fmaxf(Mx[mf][r], mx[r]);
                f[r] = exp2f(Mx[mf][r] - Mn);
                Mx[mf][r] = Mn;
                ps[r] = 0.f;
            }
#pragma unroll
            for (int nf = 0; nf < 4; ++nf)
#pragma unroll
                for (int r = 0; r < 4; ++r) {
                    const float p = exp2f(S[mf][nf][r] - Mx[mf][r]);
                    S[mf][nf][r] = p;
                    ps[r] += p;
                }
#pragma unroll
            for (int d = 1; d < 16; d <<= 1)
#pragma unroll
                for (int r = 0; r < 4; ++r)
                    ps[r] += __shfl_xor(ps[r], d, 64);
#pragma unroll
            for (int r = 0; r < 4; ++r)
                L[mf][r] = L[mf][r] * f[r] + ps[r];
#pragma unroll
            for (int nf = 0; nf < 4; ++nf)
#pragma unroll
                for (int r = 0; r < 4; ++r)
                    O[mf][nf][r] *= f[r];
#pragma unroll
            for (int nf = 0; nf < 4; ++nf)
#pragma unroll
                for (int r = 0; r < 4; ++r)
                    Ps[(mf * 16 + hi * 4 + r) * 72 + nf * 16 + l15] =
                        f2bs(S[mf][nf][r]);
        }

        // same-wave LDS write->read: wait + fence against MFMA hoisting
        asm volatile("s_waitcnt lgkmcnt(0)" ::: "memory");
        __builtin_amdgcn_sched_barrier(0);

        bf16x8 pf[2][2];
#pragma unroll
        for (int mf = 0; mf < 2; ++mf)
#pragma unroll
            for (int kf = 0; kf < 2; ++kf)
                pf[mf][kf] = *(const bf16x8*)&Ps[(mf * 16 + l15) * 72 + kf * 32 + hi * 8];

#pragma unroll
        for (int kf = 0; kf < 2; ++kf)
#pragma unroll
            for (int mf = 0; mf < 2; ++mf)
#pragma unroll
                for (int nf = 0; nf < 4; ++nf)
                    O[mf][nf] = __builtin_amdgcn_mfma_f32_16x16x32_bf16(
                        pf[mf][kf], vf[nf][kf], O[mf][nf], 0, 0, 0);
    }

    const int b = bh >> 4, head = bh & 15;
#pragma unroll
    for (int mf = 0; mf < 2; ++mf)
#pragma unroll
        for (int nf = 0; nf < 4; ++nf)
#pragma unroll
            for (int r = 0; r < 4; ++r) {
                const int q = q0 + mf * 16 + hi * 4 + r;
                const float val = O[mf][nf][r] / L[mf][r];
                att[(size_t)(b * SEQ + q) * DM + head * DH + nf * 16 + l15] = f2bs(val);
            }
}

// ---------------------------------------------------------------------------
extern "C" void kernel_launch(void* const* d_in, const int* in_sizes, int n_in,
                              void* d_out, int out_size, void* d_ws, size_t ws_size,
                              hipStream_t stream) {
    const float* x   = (const float*)d_in[0];
    const float* wq  = (const float*)d_in[1];
    const float* wk  = (const float*)d_in[2];
    const float* wv  = (const float*)d_in[3];
    const float* wp  = (const float*)d_in[4];
    const float* bp  = (const float*)d_in[5];
    const float* w1  = (const float*)d_in[6];
    const float* b1  = (const float*)d_in[7];
    const float* w2  = (const float*)d_in[8];
    const float* b2  = (const float*)d_in[9];
    const float* g1  = (const float*)d_in[10];
    const float* be1 = (const float*)d_in[11];
    const float* g2  = (const float*)d_in[12];
    const float* be2 = (const float*)d_in[13];
    float* out = (float*)d_out;

    char* ws = (char*)d_ws;
    short* wqkv_t = (short*)(ws + 0);          //  6.0 MB  [3072][1024]
    short* wp_t   = (short*)(ws + 6291456);    //  2.0 MB  [1024][1024]
    short* w1_t   = (short*)(ws + 8388608);    //  8.0 MB  [4096][1024]
    short* w2_t   = (short*)(ws + 16777216);   //  8.0 MB  [1024][4096]
    short* h      = (short*)(ws + 25165824);   // 16 MB
    short* qb     = (short*)(ws + 41943040);   // 16 MB
    short* kb     = (short*)(ws + 58720256);   // 16 MB
    short* vb     = (short*)(ws + 75497472);   // 16 MB
    short* att    = (short*)(ws + 92274688);   // 16 MB
    float* x1     = (float*)(ws + 109051904);  // 32 MB
    short* h2     = (short*)(ws + 142606336);  // 16 MB
    short* tbuf   = (short*)(ws + 25165824);   // 64 MB, aliases h/qb/kb/vb (dead)

    dim3 blk(256);

    transpose_cvt_kernel<<<dim3(16, 16), blk, 0, stream>>>(wq, wqkv_t,                1024, 1024);
    transpose_cvt_kernel<<<dim3(16, 16), blk, 0, stream>>>(wk, wqkv_t + 1024 * 1024,  1024, 1024);
    transpose_cvt_kernel<<<dim3(16, 16), blk, 0, stream>>>(wv, wqkv_t + 2048 * 1024,  1024, 1024);
    transpose_cvt_kernel<<<dim3(16, 16), blk, 0, stream>>>(wp, wp_t,                  1024, 1024);
    transpose_cvt_kernel<<<dim3(16, 64), blk, 0, stream>>>(w1, w1_t,                  1024, 4096);
    transpose_cvt_kernel<<<dim3(64, 16), blk, 0, stream>>>(w2, w2_t,                  4096, 1024);

    ln_kernel<<<MROWS, blk, 0, stream>>>(x, g1, be1, h);

    gemm_bt<0><<<dim3(64, 24), blk, 0, stream>>>(h, wqkv_t, 3072, 1024,
        nullptr, nullptr, nullptr, nullptr, qb, kb, vb);

    attn_kernel<<<dim3(64, 64), dim3(64), 0, stream>>>(qb, kb, vb, att);

    gemm_bt<1><<<dim3(64, 8), blk, 0, stream>>>(att, wp_t, 1024, 1024,
        bp, x, x1, nullptr, nullptr, nullptr, nullptr);

    ln_kernel<<<MROWS, blk, 0, stream>>>(x1, g2, be2, h2);

    gemm_bt<2><<<dim3(64, 32), blk, 0, stream>>>(h2, w1_t, 4096, 1024,
        b1, nullptr, nullptr, tbuf, nullptr, nullptr, nullptr);

    gemm_bt<1><<<dim3(64, 8), blk, 0, stream>>>(tbuf, w2_t, 1024, 4096,
        b2, x1, out, nullptr, nullptr, nullptr, nullptr);
}

// Round 3
// 473.215 us; speedup vs baseline: 1.2158x; 1.1853x over previous
//
#include <hip/hip_runtime.h>
#include <hip/hip_bf16.h>
#include <stdint.h>

// Problem constants
#define DM   1024
#define NH   16
#define DH   64
#define BATCH 4
#define SEQ  2048
#define MROWS (BATCH*SEQ)   // 8192

typedef float f32x4 __attribute__((ext_vector_type(4)));
typedef __bf16 bf16x8 __attribute__((ext_vector_type(8)));

// Q is pre-scaled by (1/sqrt(D)) * log2(e) so softmax can use exp2 directly.
#define QSCALE 0.045084220f

__device__ __forceinline__ short f2bs(float f) {
    __bf16 h = (__bf16)f;
    return __builtin_bit_cast(short, h);
}

__device__ __forceinline__ void gload_lds16(const void* g, void* l) {
    __builtin_amdgcn_global_load_lds(
        (__attribute__((address_space(1))) void*)(g),
        (__attribute__((address_space(3))) void*)(l), 16, 0, 0);
}

// ---------------------------------------------------------------------------
// Transpose + fp32->bf16 convert: wt[n][k] = bf16(w[k][n]).  64x64 tiles.
// ---------------------------------------------------------------------------
__global__ __launch_bounds__(256) void transpose_cvt_kernel(
    const float* __restrict__ w, short* __restrict__ wt, int K, int N)
{
    __shared__ short tile[64 * 65];
    const int k0 = blockIdx.x * 64, n0 = blockIdx.y * 64;
    const int t = threadIdx.x;
#pragma unroll
    for (int i = 0; i < 16; ++i) {
        int idx = i * 256 + t;
        int r = idx >> 6, c = idx & 63;
        tile[r * 65 + c] = f2bs(w[(size_t)(k0 + r) * N + n0 + c]);
    }
    __syncthreads();
#pragma unroll
    for (int i = 0; i < 16; ++i) {
        int idx = i * 256 + t;
        int r = idx >> 6, c = idx & 63;      // r: n-local, c: k-local
        wt[(size_t)(n0 + r) * K + k0 + c] = tile[c * 65 + r];
    }
}

// ---------------------------------------------------------------------------
// LayerNorm (rows of 1024 fp32) -> bf16
// ---------------------------------------------------------------------------
__global__ __launch_bounds__(256) void ln_kernel(
    const float* __restrict__ x, const float* __restrict__ g,
    const float* __restrict__ be, short* __restrict__ out)
{
    const int row = blockIdx.x, t = threadIdx.x;
    const float4 v = ((const float4*)(x + (size_t)row * DM))[t];
    float s  = v.x + v.y + v.z + v.w;
    float ss = v.x * v.x + v.y * v.y + v.z * v.z + v.w * v.w;
#pragma unroll
    for (int d = 1; d < 64; d <<= 1) {
        s  += __shfl_xor(s, d, 64);
        ss += __shfl_xor(ss, d, 64);
    }
    __shared__ float red[8];
    const int wid = t >> 6;
    if ((t & 63) == 0) { red[wid] = s; red[wid + 4] = ss; }
    __syncthreads();
    s  = red[0] + red[1] + red[2] + red[3];
    ss = red[4] + red[5] + red[6] + red[7];
    const float mu = s * (1.0f / DM);
    const float rs = rsqrtf(ss * (1.0f / DM) - mu * mu + 1e-5f);
    const float4 gg = ((const float4*)g)[t];
    const float4 bb = ((const float4*)be)[t];
    short4 o;
    o.x = f2bs((v.x - mu) * rs * gg.x + bb.x);
    o.y = f2bs((v.y - mu) * rs * gg.y + bb.y);
    o.z = f2bs((v.z - mu) * rs * gg.z + bb.z);
    o.w = f2bs((v.w - mu) * rs * gg.w + bb.w);
    ((short4*)(out + (size_t)row * DM))[t] = o;
}

// ---------------------------------------------------------------------------
// GEMM: C[M,N] = A[M,K] @ B[K,N], A bf16 row-major, Bt bf16 [N][K].
// 128x128 tile, BK=32, 4 waves (2x2), each wave 64x64 via 4x4 mfma 16x16x32.
// EPI 0: QKV scatter (Q scaled by QSCALE, Q,K -> [BH,T,64]; V -> [BH,64,T])
// EPI 1: out fp32 = acc + bias[n] + res[m,n]
// EPI 2: out bf16 = relu(acc + bias[n])
// ---------------------------------------------------------------------------
template<int EPI>
__global__ __launch_bounds__(256) void gemm_bt(
    const short* __restrict__ A, const short* __restrict__ Bt,
    int N, int K,
    const float* __restrict__ bias, const float* __restrict__ res,
    float* __restrict__ outf, short* __restrict__ outb,
    short* __restrict__ qo, short* __restrict__ ko, short* __restrict__ vo)
{
    __shared__ short As[128 * 32];
    __shared__ short Bs[128 * 32];
    const int t = threadIdx.x;
    const int lane = t & 63;
    const int l15 = lane & 15, hi = lane >> 4;
    const int wid = t >> 6;
    const int wm = (wid & 1) * 64, wn = (wid >> 1) * 64;
    const int m0 = blockIdx.x * 128, n0 = blockIdx.y * 128;

    f32x4 acc[4][4] = {};

    const int ra = t >> 2;            // row for staging chunk (0..63)
    const int ca = (t & 3) * 8;       // k-offset in shorts

    for (int k0 = 0; k0 < K; k0 += 32) {
        gload_lds16(A  + (size_t)(m0 + ra)      * K + k0 + ca, &As[t * 8]);
        gload_lds16(A  + (size_t)(m0 + ra + 64) * K + k0 + ca, &As[(t + 256) * 8]);
        gload_lds16(Bt + (size_t)(n0 + ra)      * K + k0 + ca, &Bs[t * 8]);
        gload_lds16(Bt + (size_t)(n0 + ra + 64) * K + k0 + ca, &Bs[(t + 256) * 8]);
        __syncthreads();
        bf16x8 af[4], bfr[4];
#pragma unroll
        for (int i = 0; i < 4; ++i)
            af[i] = *(const bf16x8*)&As[(wm + i * 16 + l15) * 32 + hi * 8];
#pragma unroll
        for (int j = 0; j < 4; ++j)
            bfr[j] = *(const bf16x8*)&Bs[(wn + j * 16 + l15) * 32 + hi * 8];
#pragma unroll
        for (int i = 0; i < 4; ++i)
#pragma unroll
            for (int j = 0; j < 4; ++j)
                acc[i][j] = __builtin_amdgcn_mfma_f32_16x16x32_bf16(
                    af[i], bfr[j], acc[i][j], 0, 0, 0);
        __syncthreads();
    }

    const int rbase = m0 + wm + hi * 4;
    const int cb = n0 + wn + l15;
#pragma unroll
    for (int i = 0; i < 4; ++i) {
#pragma unroll
        for (int j = 0; j < 4; ++j) {
            const int nn = cb + j * 16;
            if constexpr (EPI == 0) {
                const int mat = nn >> 10, n1 = nn & 1023;
                const int head = n1 >> 6, dh = n1 & 63;
                if (mat == 2) {
                    // V: 4 consecutive tokens -> one short4 store
                    const int m = rbase + i * 16;
                    const int b = m >> 11, tok = m & 2047;
                    short4 pk;
                    pk.x = f2bs(acc[i][j][0]);
                    pk.y = f2bs(acc[i][j][1]);
                    pk.z = f2bs(acc[i][j][2]);
                    pk.w = f2bs(acc[i][j][3]);
                    *(short4*)&vo[((size_t)(b * NH + head) * DH + dh) * SEQ + tok] = pk;
                } else {
                    const float sc = (mat == 0) ? QSCALE : 1.0f;
#pragma unroll
                    for (int r = 0; r < 4; ++r) {
                        const int m = rbase + i * 16 + r;
                        const int b = m >> 11, tok = m & 2047;
                        const size_t bh = (size_t)(b * NH + head);
                        const short v = f2bs(acc[i][j][r] * sc);
                        if (mat == 0) qo[(bh * SEQ + tok) * DH + dh] = v;
                        else          ko[(bh * SEQ + tok) * DH + dh] = v;
                    }
                }
            } else if constexpr (EPI == 1) {
#pragma unroll
                for (int r = 0; r < 4; ++r) {
                    const int m = rbase + i * 16 + r;
                    outf[(size_t)m * N + nn] =
                        acc[i][j][r] + bias[nn] + res[(size_t)m * N + nn];
                }
            } else {
#pragma unroll
                for (int r = 0; r < 4; ++r) {
                    const int m = rbase + i * 16 + r;
                    float z = acc[i][j][r] + bias[nn];
                    outb[(size_t)m * N + nn] = f2bs(z > 0.f ? z : 0.f);
                }
            }
        }
    }
}

// ---------------------------------------------------------------------------
// Causal flash attention, balanced: ONE wave per (bh, q-tile pair (p, 63-p)).
// Every wave processes a constant ~34.5 KV tiles -> no straggler tail.
// Flat grid of 2048 blocks; bh = n & 63 so all blocks of a bh hit one XCD
// (n % 8 == bh % 8) and its K/V (512 KB) stays in that XCD's 4 MB L2.
// Q: [BH,T,64] bf16 (pre-scaled). K: [BH,T,64]. Vt: [BH,64,T].
// out att: [B*T, 1024] bf16.  grid = (2048), block = 64.
// ---------------------------------------------------------------------------
__global__ __launch_bounds__(64) void attn_kernel(
    const short* __restrict__ Q, const short* __restrict__ Kx,
    const short* __restrict__ Vt, short* __restrict__ att)
{
    __shared__ short Ps[32 * 72];

    const int n  = blockIdx.x;
    const int bh = n & 63;
    const int p  = n >> 6;                   // 0..31
    const int lane = threadIdx.x;
    const int l15 = lane & 15, hi = lane >> 4;
    const size_t base = (size_t)bh * (SEQ * DH);
    const int b = bh >> 4, head = bh & 15;

    for (int half = 0; half < 2; ++half) {
        const int qi = half ? (63 - p) : p;
        const int q0 = qi * 32;

        bf16x8 qf[2][2];
#pragma unroll
        for (int mf = 0; mf < 2; ++mf)
#pragma unroll
            for (int kf = 0; kf < 2; ++kf)
                qf[mf][kf] = *(const bf16x8*)
                    &Q[base + (size_t)(q0 + mf * 16 + l15) * DH + kf * 32 + hi * 8];

        f32x4 O[2][4] = {};
        float Mx[2][4], L[2][4];
#pragma unroll
        for (int mf = 0; mf < 2; ++mf)
#pragma unroll
            for (int r = 0; r < 4; ++r) { Mx[mf][r] = -3.0e38f; L[mf][r] = 0.f; }

        const int nkv = (q0 + 95) >> 6;
        for (int it = 0; it < nkv; ++it) {
            const int kv0 = it * 64;

            bf16x8 kfr[4][2];
#pragma unroll
            for (int nf = 0; nf < 4; ++nf)
#pragma unroll
                for (int kf = 0; kf < 2; ++kf)
                    kfr[nf][kf] = *(const bf16x8*)
                        &Kx[base + (size_t)(kv0 + nf * 16 + l15) * DH + kf * 32 + hi * 8];

            f32x4 S[2][4] = {};
#pragma unroll
            for (int kf = 0; kf < 2; ++kf)
#pragma unroll
                for (int mf = 0; mf < 2; ++mf)
#pragma unroll
                    for (int nf = 0; nf < 4; ++nf)
                        S[mf][nf] = __builtin_amdgcn_mfma_f32_16x16x32_bf16(
                            qf[mf][kf], kfr[nf][kf], S[mf][nf], 0, 0, 0);

            // prefetch V fragments (B-operand: rows = dh, k = kv)
            bf16x8 vf[4][2];
#pragma unroll
            for (int nf = 0; nf < 4; ++nf)
#pragma unroll
                for (int kf = 0; kf < 2; ++kf)
                    vf[nf][kf] = *(const bf16x8*)
                        &Vt[base + (size_t)(nf * 16 + l15) * SEQ + kv0 + kf * 32 + hi * 8];

            if (kv0 + 63 > q0) {   // causal tail masking
#pragma unroll
                for (int mf = 0; mf < 2; ++mf)
#pragma unroll
                    for (int nf = 0; nf < 4; ++nf)
#pragma unroll
                        for (int r = 0; r < 4; ++r) {
                            const int q  = q0 + mf * 16 + hi * 4 + r;
                            const int kv = kv0 + nf * 16 + l15;
                            if (kv > q) S[mf][nf][r] = -3.0e38f;
                        }
            }

#pragma unroll
            for (int mf = 0; mf < 2; ++mf) {
                float mx[4], f[4], ps[4];
#pragma unroll
                for (int r = 0; r < 4; ++r)
                    mx[r] = fmaxf(fmaxf(S[mf][0][r], S[mf][1][r]),
                                  fmaxf(S[mf][2][r], S[mf][3][r]));
#pragma unroll
                for (int d = 1; d < 16; d <<= 1)
#pragma unroll
                    for (int r = 0; r < 4; ++r)
                        mx[r] = fmaxf(mx[r], __shfl_xor(mx[r], d, 64));
#pragma unroll
                for (int r = 0; r < 4; ++r) {
                    const float Mn = fmaxf(Mx[mf][r], mx[r]);
                    f[r] = exp2f(Mx[mf][r] - Mn);
                    Mx[mf][r] = Mn;
                    ps[r] = 0.f;
                }
#pragma unroll
                for (int nf = 0; nf < 4; ++nf)
#pragma unroll
                    for (int r = 0; r < 4; ++r) {
                        const float pv = exp2f(S[mf][nf][r] - Mx[mf][r]);
                        S[mf][nf][r] = pv;
                        ps[r] += pv;
                    }
#pragma unroll
                for (int d = 1; d < 16; d <<= 1)
#pragma unroll
                    for (int r = 0; r < 4; ++r)
                        ps[r] += __shfl_xor(ps[r], d, 64);
#pragma unroll
                for (int r = 0; r < 4; ++r)
                    L[mf][r] = L[mf][r] * f[r] + ps[r];
#pragma unroll
                for (int nf = 0; nf < 4; ++nf)
#pragma unroll
                    for (int r = 0; r < 4; ++r)
                        O[mf][nf][r] *= f[r];
#pragma unroll
                for (int nf = 0; nf < 4; ++nf)
#pragma unroll
                    for (int r = 0; r < 4; ++r)
                        Ps[(mf * 16 + hi * 4 + r) * 72 + nf * 16 + l15] =
                            f2bs(S[mf][nf][r]);
            }

            // same-wave LDS write->read: wait + fence against MFMA hoisting
            asm volatile("s_waitcnt lgkmcnt(0)" ::: "memory");
            __builtin_amdgcn_sched_barrier(0);

            bf16x8 pf[2][2];
#pragma unroll
            for (int mf = 0; mf < 2; ++mf)
#pragma unroll
                for (int kf = 0; kf < 2; ++kf)
                    pf[mf][kf] = *(const bf16x8*)&Ps[(mf * 16 + l15) * 72 + kf * 32 + hi * 8];

#pragma unroll
            for (int kf = 0; kf < 2; ++kf)
#pragma unroll
                for (int mf = 0; mf < 2; ++mf)
#pragma unroll
                    for (int nf = 0; nf < 4; ++nf)
                        O[mf][nf] = __builtin_amdgcn_mfma_f32_16x16x32_bf16(
                            pf[mf][kf], vf[nf][kf], O[mf][nf], 0, 0, 0);
        }

#pragma unroll
        for (int mf = 0; mf < 2; ++mf)
#pragma unroll
            for (int nf = 0; nf < 4; ++nf)
#pragma unroll
                for (int r = 0; r < 4; ++r) {
                    const int q = q0 + mf * 16 + hi * 4 + r;
                    const float val = O[mf][nf][r] / L[mf][r];
                    att[(size_t)(b * SEQ + q) * DM + head * DH + nf * 16 + l15] = f2bs(val);
                }
    }
}

// ---------------------------------------------------------------------------
extern "C" void kernel_launch(void* const* d_in, const int* in_sizes, int n_in,
                              void* d_out, int out_size, void* d_ws, size_t ws_size,
                              hipStream_t stream) {
    const float* x   = (const float*)d_in[0];
    const float* wq  = (const float*)d_in[1];
    const float* wk  = (const float*)d_in[2];
    const float* wv  = (const float*)d_in[3];
    const float* wp  = (const float*)d_in[4];
    const float* bp  = (const float*)d_in[5];
    const float* w1  = (const float*)d_in[6];
    const float* b1  = (const float*)d_in[7];
    const float* w2  = (const float*)d_in[8];
    const float* b2  = (const float*)d_in[9];
    const float* g1  = (const float*)d_in[10];
    const float* be1 = (const float*)d_in[11];
    const float* g2  = (const float*)d_in[12];
    const float* be2 = (const float*)d_in[13];
    float* out = (float*)d_out;

    char* ws = (char*)d_ws;
    short* wqkv_t = (short*)(ws + 0);          //  6.0 MB  [3072][1024]
    short* wp_t   = (short*)(ws + 6291456);    //  2.0 MB  [1024][1024]
    short* w1_t   = (short*)(ws + 8388608);    //  8.0 MB  [4096][1024]
    short* w2_t   = (short*)(ws + 16777216);   //  8.0 MB  [1024][4096]
    short* h      = (short*)(ws + 25165824);   // 16 MB
    short* qb     = (short*)(ws + 41943040);   // 16 MB
    short* kb     = (short*)(ws + 58720256);   // 16 MB
    short* vb     = (short*)(ws + 75497472);   // 16 MB
    short* att    = (short*)(ws + 92274688);   // 16 MB
    float* x1     = (float*)(ws + 109051904);  // 32 MB
    short* h2     = (short*)(ws + 142606336);  // 16 MB
    short* tbuf   = (short*)(ws + 25165824);   // 64 MB, aliases h/qb/kb/vb (dead)

    dim3 blk(256);

    transpose_cvt_kernel<<<dim3(16, 16), blk, 0, stream>>>(wq, wqkv_t,                1024, 1024);
    transpose_cvt_kernel<<<dim3(16, 16), blk, 0, stream>>>(wk, wqkv_t + 1024 * 1024,  1024, 1024);
    transpose_cvt_kernel<<<dim3(16, 16), blk, 0, stream>>>(wv, wqkv_t + 2048 * 1024,  1024, 1024);
    transpose_cvt_kernel<<<dim3(16, 16), blk, 0, stream>>>(wp, wp_t,                  1024, 1024);
    transpose_cvt_kernel<<<dim3(16, 64), blk, 0, stream>>>(w1, w1_t,                  1024, 4096);
    transpose_cvt_kernel<<<dim3(64, 16), blk, 0, stream>>>(w2, w2_t,                  4096, 1024);

    ln_kernel<<<MROWS, blk, 0, stream>>>(x, g1, be1, h);

    gemm_bt<0><<<dim3(64, 24), blk, 0, stream>>>(h, wqkv_t, 3072, 1024,
        nullptr, nullptr, nullptr, nullptr, qb, kb, vb);

    attn_kernel<<<dim3(2048), dim3(64), 0, stream>>>(qb, kb, vb, att);

    gemm_bt<1><<<dim3(64, 8), blk, 0, stream>>>(att, wp_t, 1024, 1024,
        bp, x, x1, nullptr, nullptr, nullptr, nullptr);

    ln_kernel<<<MROWS, blk, 0, stream>>>(x1, g2, be2, h2);

    gemm_bt<2><<<dim3(64, 32), blk, 0, stream>>>(h2, w1_t, 4096, 1024,
        b1, nullptr, nullptr, tbuf, nullptr, nullptr, nullptr);

    gemm_bt<1><<<dim3(64, 8), blk, 0, stream>>>(tbuf, w2_t, 1024, 4096,
        b2, x1, out, nullptr, nullptr, nullptr, nullptr);
}